// Round 1
// baseline (22598.537 us; speedup 1.0000x reference)
//
#include <hip/hip_runtime.h>
#include <math.h>
#include <string.h>

#define PI_D 3.14159265358979323846264338327950288

// ---------------------------------------------------------------------------
// Scattering2D (J=4, L=8, 256x256, B=16) + MLP, all fp32.
// 2D FFT = row-Stockham-FFT-with-transposed-write applied twice.
// Subsampling is done as spectrum folding fused into pass-1 load.
// ---------------------------------------------------------------------------

enum { IN_COMPLEX = 0, IN_REAL = 1, IN_MULFOLD = 2 };
enum { OUT_COMPLEX = 0, OUT_ABS = 1, OUT_REAL_S = 2 };

struct RftParams {
  const float2* srcC;
  const float*  srcR;
  const float*  filt;
  float2* dstC;
  float*  dstR;
  int m1;        // source resolution for MULFOLD
  int srcDiv;    // source image = img / srcDiv
  int filtMod;   // filter index = img % filtMod
  float scale;   // ifft scale (1/m1^2), applied at load
  float sign;    // -1 forward, +1 inverse
  int chDiv, chBase, b0;   // S-write addressing
  int inMode, outMode;
};

template<int M>
__global__ __launch_bounds__(256) void rft_kernel(RftParams p) {
  constexpr int R = (M >= 64) ? 8 : ((M == 32) ? 16 : 32);   // rows per block
  constexpr int T = (M == 16) ? 4 : ((M == 32) ? 5 : ((M == 64) ? 6 : ((M == 128) ? 7 : 8)));
  __shared__ float2 Abuf[R][M + 1];
  __shared__ float2 Bbuf[R][M + 1];
  __shared__ float2 W[M / 2];
  const int tid = threadIdx.x;
  const long rows0 = (long)blockIdx.x * R;

  // twiddle table: W[q] = exp(sign * 2*pi*i * q / M)
  {
    const float base = p.sign * 6.28318530717958647692f / (float)M;
    for (int i = tid; i < M / 2; i += 256) {
      float sv, cv;
      sincosf(base * (float)i, &sv, &cv);
      W[i] = make_float2(cv, sv);
    }
  }

  // ---- load R rows of length M into Abuf ----
  if (p.inMode == IN_COMPLEX) {
    const float2* s = p.srcC + rows0 * M;
    for (int idx = tid; idx < R * M; idx += 256)
      Abuf[idx / M][idx % M] = s[idx];
  } else if (p.inMode == IN_REAL) {
    const float* s = p.srcR + rows0 * M;
    for (int idx = tid; idx < R * M; idx += 256)
      Abuf[idx / M][idx % M] = make_float2(s[idx], 0.f);
  } else {  // IN_MULFOLD: spectrum * filter, folded from m1^2 down to M^2
    const int m1 = p.m1;
    const int k = m1 / M;
    for (int idx = tid; idx < R * M; idx += 256) {
      const int rl = idx / M, c = idx % M;
      const long g = rows0 + rl;
      const long img = g / M;
      const int r = (int)(g - img * M);
      const float2* sp = p.srcC + (img / p.srcDiv) * (long)m1 * m1;
      const float* fp = p.filt + (long)(img % p.filtMod) * m1 * m1;
      float re = 0.f, im = 0.f;
      for (int qr = 0; qr < k; qr++) {
        const long ro = (long)(r + qr * M) * m1;
        const float2* srow = sp + ro;
        const float*  frow = fp + ro;
        for (int qc = 0; qc < k; qc++) {
          const int cc = c + qc * M;
          const float2 v = srow[cc];
          const float fv = frow[cc];
          re = fmaf(v.x, fv, re);
          im = fmaf(v.y, fv, im);
        }
      }
      Abuf[rl][c] = make_float2(re * p.scale, im * p.scale);
    }
  }
  __syncthreads();

  // ---- Stockham radix-2 DIF (autosort), T stages, ping-pong A<->B ----
  #pragma unroll
  for (int t = 0; t < T; t++) {
    const int s = 1 << t;
    float2 (*Src)[M + 1] = (t & 1) ? Bbuf : Abuf;
    float2 (*Dst)[M + 1] = (t & 1) ? Abuf : Bbuf;
    for (int bf = tid; bf < R * (M / 2); bf += 256) {
      const int row = bf / (M / 2);
      const int j = bf - row * (M / 2);
      const float2 a = Src[row][j];
      const float2 b = Src[row][j + M / 2];
      const float2 w = W[j & ~(s - 1)];
      const float vx = a.x - b.x, vy = a.y - b.y;
      const int dc = (j & (s - 1)) + ((j >> t) << (t + 1));
      Dst[row][dc] = make_float2(a.x + b.x, a.y + b.y);
      Dst[row][dc + s] = make_float2(vx * w.x - vy * w.y, vx * w.y + vy * w.x);
    }
    __syncthreads();
  }
  float2 (*P)[M + 1] = (T & 1) ? Bbuf : Abuf;

  // ---- store transposed: out[img][fo][rpos] = FFT(row rpos)[fo] ----
  if (p.outMode == OUT_COMPLEX) {
    for (int idx = tid; idx < R * M; idx += 256) {
      const int rl = idx & (R - 1);
      const int fo = idx / R;
      const long g = rows0 + rl;
      const long img = g / M;
      const int rpos = (int)(g - img * M);
      p.dstC[img * (long)M * M + (long)fo * M + rpos] = P[rl][fo];
    }
  } else if (p.outMode == OUT_ABS) {
    for (int idx = tid; idx < R * M; idx += 256) {
      const int rl = idx & (R - 1);
      const int fo = idx / R;
      const long g = rows0 + rl;
      const long img = g / M;
      const int rpos = (int)(g - img * M);
      const float2 z = P[rl][fo];
      p.dstR[img * (long)M * M + (long)fo * M + rpos] = sqrtf(z.x * z.x + z.y * z.y);
    }
  } else {  // OUT_REAL_S (M == 16): scatter Re into S[b][ch][16][16]
    for (int idx = tid; idx < R * M; idx += 256) {
      const int rl = idx & (R - 1);
      const int fo = idx / R;
      const long g = rows0 + rl;
      const long img = g / M;
      const int rpos = (int)(g - img * M);
      const int bidx = (int)(img / p.chDiv) + p.b0;
      const int ch = p.chBase + (int)(img % p.chDiv);
      p.dstR[((long)bidx * 417 + ch) * 256 + fo * M + rpos] = P[rl][fo].x;
    }
  }
}

static void rft_go(int M, int nimg, const RftParams& p, hipStream_t st) {
  const int R = (M >= 64) ? 8 : ((M == 32) ? 16 : 32);
  const int blocks = nimg * M / R;
  switch (M) {
    case 256: rft_kernel<256><<<blocks, 256, 0, st>>>(p); break;
    case 128: rft_kernel<128><<<blocks, 256, 0, st>>>(p); break;
    case  64: rft_kernel< 64><<<blocks, 256, 0, st>>>(p); break;
    case  32: rft_kernel< 32><<<blocks, 256, 0, st>>>(p); break;
    case  16: rft_kernel< 16><<<blocks, 256, 0, st>>>(p); break;
  }
}

// ---------------------------------------------------------------------------
// Filter banks (computed on device in f64, mirroring numpy exactly)
// PSI banks: (r,js) = (0,0)(0,1)(0,2)(0,3)(1,1)(1,2)(2,1), 8 orientations each
// ---------------------------------------------------------------------------
__device__ const long PSI_CUM[7] = {524288, 1048576, 1572864, 2097152, 2228224, 2359296, 2392064};
__device__ const int  PSI_MM[7]  = {256, 256, 256, 256, 128, 128, 64};
__device__ const int  PSI_JS[7]  = {0, 1, 2, 3, 1, 2, 1};

__device__ __forceinline__ double dfreq(int i, int m) {
  return (double)((i < (m >> 1)) ? i : i - m) / (double)m;
}

__global__ void build_psi_kernel(float* psi, int* fmax) {
  const long i = (long)blockIdx.x * 256 + threadIdx.x;
  if (i >= 2392064L) return;
  int bank = 0;
  while (i >= PSI_CUM[bank]) bank++;
  const long base = bank ? PSI_CUM[bank - 1] : 0;
  const long rem = i - base;
  const int m = PSI_MM[bank], js = PSI_JS[bank];
  const long mm2 = (long)m * m;
  const int l = (int)(rem / mm2);
  const long pos = rem - (long)l * mm2;
  const int r = (int)(pos / m), c = (int)(pos - (long)r * m);
  const double sigma = 0.8 * (double)(1 << js);
  const double xi = (3.0 * PI_D / 4.0) / (double)(1 << js);
  const double th = (double)l * PI_D / 8.0;
  const double kx = 2.0 * PI_D * dfreq(r, m);
  const double ky = 2.0 * PI_D * dfreq(c, m);
  const double ct = cos(th), st = sin(th);
  const double w1 = kx * ct + ky * st;
  const double w2 = -kx * st + ky * ct;
  const double s2 = sigma * sigma;
  const double aa  = exp(-0.5 * s2 * ((w1 - xi) * (w1 - xi) + 0.25 * w2 * w2));
  const double env = exp(-0.5 * s2 * (w1 * w1 + 0.25 * w2 * w2));
  const double beta = exp(-0.5 * s2 * xi * xi);
  const double f = aa - beta * env;
  psi[i] = (float)f;
  // max is positive (~0.97); int-compare valid for non-negative floats
  atomicMax(&fmax[bank * 8 + l], __float_as_int(fmaxf((float)f, 0.f)));
}

__global__ void norm_psi_kernel(float* psi, const int* fmax) {
  const long i = (long)blockIdx.x * 256 + threadIdx.x;
  if (i >= 2392064L) return;
  int bank = 0;
  while (i >= PSI_CUM[bank]) bank++;
  const long base = bank ? PSI_CUM[bank - 1] : 0;
  const long rem = i - base;
  const int m = PSI_MM[bank];
  const int l = (int)(rem / ((long)m * m));
  const float mx = fmaxf(__int_as_float(fmax[bank * 8 + l]), 1e-12f);
  psi[i] = psi[i] / mx;
}

__global__ void build_phi_kernel(float* phi) {
  const long i = (long)blockIdx.x * 256 + threadIdx.x;
  if (i >= 87040L) return;
  int rr; long base;
  if (i < 65536) { rr = 0; base = 0; }
  else if (i < 81920) { rr = 1; base = 65536; }
  else if (i < 86016) { rr = 2; base = 81920; }
  else { rr = 3; base = 86016; }
  const int m = 256 >> rr;
  const double sigma = 0.8 * (double)(1 << (4 - rr));
  const long pos = i - base;
  const int r = (int)(pos / m), c = (int)(pos % m);
  const double kx = 2.0 * PI_D * dfreq(r, m);
  const double ky = 2.0 * PI_D * dfreq(c, m);
  phi[i] = (float)exp(-0.5 * sigma * sigma * (kx * kx + ky * ky));
}

// ---------------------------------------------------------------------------
// MLP
// ---------------------------------------------------------------------------
__global__ __launch_bounds__(256) void mlp1_kernel(const float* __restrict__ S,
                                                   const float* __restrict__ w1,
                                                   float* __restrict__ out1) {
  __shared__ float hs[16][256];
  const int o = blockIdx.x * 256 + threadIdx.x;   // 1024 outputs over 4 blocks
  const int ch = blockIdx.y;                      // 417 k-chunks of 256
  for (int idx = threadIdx.x; idx < 16 * 256; idx += 256) {
    const int b = idx >> 8, kk = idx & 255;
    hs[b][kk] = S[((long)b * 417 + ch) * 256 + kk];
  }
  __syncthreads();
  float acc[16];
  #pragma unroll
  for (int b = 0; b < 16; b++) acc[b] = 0.f;
  const float* wp = w1 + (long)ch * 256 * 1024 + o;
  for (int kk = 0; kk < 256; kk++) {
    const float w = wp[(long)kk * 1024];
    #pragma unroll
    for (int b = 0; b < 16; b++) acc[b] = fmaf(hs[b][kk], w, acc[b]);
  }
  #pragma unroll
  for (int b = 0; b < 16; b++) atomicAdd(&out1[b * 1024 + o], acc[b]);
}

__global__ void l1post_kernel(const float* out1, const float* b1, const float* g,
                              const float* bb, const float* mm, const float* vv, float* h1) {
  const int i = blockIdx.x * 256 + threadIdx.x;
  if (i < 16384) {
    const int o = i & 1023;
    const float xv = fmaxf(out1[i] + b1[o], 0.f);
    const float rs = (float)(1.0 / sqrt((double)vv[o] + 1e-5));
    h1[i] = (xv - mm[o]) * rs * g[o] + bb[o];
  }
}

__global__ __launch_bounds__(256) void mlp2_kernel(const float* h1, const float* w2, const float* b2,
                                                   const float* g, const float* bb, const float* mm,
                                                   const float* vv, float* h2) {
  __shared__ float hs[16][256];
  const int o = blockIdx.x * 256 + threadIdx.x;   // 512 outputs over 2 blocks
  float acc[16];
  #pragma unroll
  for (int b = 0; b < 16; b++) acc[b] = 0.f;
  for (int kc = 0; kc < 4; kc++) {
    __syncthreads();
    for (int idx = threadIdx.x; idx < 16 * 256; idx += 256) {
      const int b = idx >> 8, kk = idx & 255;
      hs[b][kk] = h1[b * 1024 + kc * 256 + kk];
    }
    __syncthreads();
    for (int kk = 0; kk < 256; kk++) {
      const float w = w2[(long)(kc * 256 + kk) * 512 + o];
      #pragma unroll
      for (int b = 0; b < 16; b++) acc[b] = fmaf(hs[b][kk], w, acc[b]);
    }
  }
  const float bias = b2[o], gg = g[o], bbv = bb[o], mv = mm[o];
  const float rs = (float)(1.0 / sqrt((double)vv[o] + 1e-5));
  for (int b = 0; b < 16; b++) {
    const float xv = fmaxf(acc[b] + bias, 0.f);
    h2[b * 512 + o] = (xv - mv) * rs * gg + bbv;
  }
}

__global__ __launch_bounds__(128) void mlp3_kernel(const float* h2, const float* w3, const float* b3,
                                                   const float* g, const float* bb, const float* mm,
                                                   const float* vv, float* h3) {
  __shared__ float hs[16][256];
  const int o = threadIdx.x;   // 128 outputs
  float acc[16];
  #pragma unroll
  for (int b = 0; b < 16; b++) acc[b] = 0.f;
  for (int kc = 0; kc < 2; kc++) {
    __syncthreads();
    for (int idx = threadIdx.x; idx < 16 * 256; idx += 128) {
      const int b = idx >> 8, kk = idx & 255;
      hs[b][kk] = h2[b * 512 + kc * 256 + kk];
    }
    __syncthreads();
    for (int kk = 0; kk < 256; kk++) {
      const float w = w3[(kc * 256 + kk) * 128 + o];
      #pragma unroll
      for (int b = 0; b < 16; b++) acc[b] = fmaf(hs[b][kk], w, acc[b]);
    }
  }
  const float bias = b3[o], gg = g[o], bbv = bb[o], mv = mm[o];
  const float rs = (float)(1.0 / sqrt((double)vv[o] + 1e-5));
  for (int b = 0; b < 16; b++) {
    const float xv = fmaxf(acc[b] + bias, 0.f);
    h3[b * 128 + o] = (xv - mv) * rs * gg + bbv;
  }
}

__global__ void mlp4_kernel(const float* h3, const float* w4, const float* b4, float* out) {
  const int b = threadIdx.x;
  if (b < 16) {
    double a = 0.0;
    for (int k = 0; k < 128; k++) a += (double)h3[b * 128 + k] * (double)w4[k];
    out[b] = (float)(a + (double)b4[0]);
  }
}

// ---------------------------------------------------------------------------
// Orchestration
// ---------------------------------------------------------------------------
static RftParams rp0() {
  RftParams p;
  memset(&p, 0, sizeof(p));
  p.srcDiv = 1; p.filtMod = 1; p.chDiv = 1;
  p.scale = 1.f; p.sign = -1.f; p.m1 = 0;
  return p;
}

extern "C" void kernel_launch(void* const* d_in, const int* in_sizes, int n_in,
                              void* d_out, int out_size, void* d_ws, size_t ws_size,
                              hipStream_t stream) {
  (void)in_sizes; (void)n_in; (void)out_size; (void)ws_size;
  const float* x    = (const float*)d_in[0];
  const float* w1   = (const float*)d_in[1];
  const float* b1   = (const float*)d_in[2];
  const float* bn1g = (const float*)d_in[3];
  const float* bn1b = (const float*)d_in[4];
  const float* bn1m = (const float*)d_in[5];
  const float* bn1v = (const float*)d_in[6];
  const float* w2   = (const float*)d_in[7];
  const float* b2   = (const float*)d_in[8];
  const float* bn2g = (const float*)d_in[9];
  const float* bn2b = (const float*)d_in[10];
  const float* bn2m = (const float*)d_in[11];
  const float* bn2v = (const float*)d_in[12];
  const float* w3   = (const float*)d_in[13];
  const float* b3   = (const float*)d_in[14];
  const float* bn3g = (const float*)d_in[15];
  const float* bn3b = (const float*)d_in[16];
  const float* bn3m = (const float*)d_in[17];
  const float* bn3v = (const float*)d_in[18];
  const float* w4   = (const float*)d_in[19];
  const float* b4   = (const float*)d_in[20];

  char* ws = (char*)d_ws;
  float2* XF   = (float2*)(ws + 0);            //  8 MiB: fft2(x), 16 x 256^2
  float2* U1F  = (float2*)(ws + 8388608);      // 64 MiB: fft2(u1), up to 128 x 256^2
  float2* BUF1 = (float2*)(ws + 75497472);     // 64 MiB ping
  float2* BUF2 = (float2*)(ws + 142606336);    // 64 MiB pong (u1/u2 real alias here)
  float*  S    = (float*)(ws + 209715200);     // 16 x 417 x 256 scattering output
  float*  PSI  = (float*)(ws + 216547328);     // 2392064 floats
  float*  PHI  = (float*)(ws + 226115584);     // 87040 floats
  int*    FMAX = (int*)(ws + 226463744);       // 56 slots
  float*  OUT1 = (float*)(ws + 226464000);     // 16 x 1024
  float*  H1   = (float*)(ws + 226529536);
  float*  H2   = (float*)(ws + 226595072);
  float*  H3   = (float*)(ws + 226627840);

  static const int psioff[7] = {0, 524288, 1048576, 1572864, 2097152, 2228224, 2359296};
  static const int phioff[4] = {0, 65536, 81920, 86016};

  // ---- filters (deterministic, rebuilt every call) ----
  hipMemsetAsync(FMAX, 0, 256, stream);
  build_psi_kernel<<<9344, 256, 0, stream>>>(PSI, FMAX);
  norm_psi_kernel<<<9344, 256, 0, stream>>>(PSI, FMAX);
  build_phi_kernel<<<340, 256, 0, stream>>>(PHI);

  // ---- Xf = fft2(x) ----
  { RftParams p = rp0(); p.inMode = IN_REAL; p.srcR = x; p.outMode = OUT_COMPLEX; p.dstC = BUF1; p.sign = -1.f; rft_go(256, 16, p, stream); }
  { RftParams p = rp0(); p.inMode = IN_COMPLEX; p.srcC = BUF1; p.outMode = OUT_COMPLEX; p.dstC = XF; p.sign = -1.f; rft_go(256, 16, p, stream); }

  // ---- s0 = Re(ifft16(fold(Xf*phi0))) ----
  { RftParams p = rp0(); p.inMode = IN_MULFOLD; p.srcC = XF; p.filt = PHI + phioff[0]; p.m1 = 256; p.srcDiv = 1; p.filtMod = 1; p.scale = 1.f / 65536.f; p.sign = 1.f; p.outMode = OUT_COMPLEX; p.dstC = BUF1; rft_go(16, 16, p, stream); }
  { RftParams p = rp0(); p.inMode = IN_COMPLEX; p.srcC = BUF1; p.sign = 1.f; p.outMode = OUT_REAL_S; p.dstR = S; p.chDiv = 1; p.chBase = 0; p.b0 = 0; rft_go(16, 16, p, stream); }

  for (int j1 = 0; j1 < 4; j1++) {
    const int m1 = 256 >> j1;
    const float isc1 = 1.f / (float)(m1 * m1);
    // u1 = |ifft_m1(fold(Xf * psi_(0,j1)))|   (128 images: (b,l1))
    { RftParams p = rp0(); p.inMode = IN_MULFOLD; p.srcC = XF; p.filt = PSI + psioff[j1]; p.m1 = 256; p.srcDiv = 8; p.filtMod = 8; p.scale = 1.f / 65536.f; p.sign = 1.f; p.outMode = OUT_COMPLEX; p.dstC = BUF1; rft_go(m1, 128, p, stream); }
    { RftParams p = rp0(); p.inMode = IN_COMPLEX; p.srcC = BUF1; p.sign = 1.f; p.outMode = OUT_ABS; p.dstR = (float*)BUF2; rft_go(m1, 128, p, stream); }
    // u1f = fft2(u1)
    { RftParams p = rp0(); p.inMode = IN_REAL; p.srcR = (const float*)BUF2; p.sign = -1.f; p.outMode = OUT_COMPLEX; p.dstC = BUF1; rft_go(m1, 128, p, stream); }
    { RftParams p = rp0(); p.inMode = IN_COMPLEX; p.srcC = BUF1; p.sign = -1.f; p.outMode = OUT_COMPLEX; p.dstC = U1F; rft_go(m1, 128, p, stream); }
    // s1 = Re(ifft16(fold(u1f * phi_j1)))
    { RftParams p = rp0(); p.inMode = IN_MULFOLD; p.srcC = U1F; p.filt = PHI + phioff[j1]; p.m1 = m1; p.srcDiv = 1; p.filtMod = 1; p.scale = isc1; p.sign = 1.f; p.outMode = OUT_COMPLEX; p.dstC = BUF1; rft_go(16, 128, p, stream); }
    { RftParams p = rp0(); p.inMode = IN_COMPLEX; p.srcC = BUF1; p.sign = 1.f; p.outMode = OUT_REAL_S; p.dstR = S; p.chDiv = 8; p.chBase = 1 + 8 * j1; p.b0 = 0; rft_go(16, 128, p, stream); }

    for (int j2 = j1 + 1; j2 < 4; j2++) {
      const int m2 = 256 >> j2;
      const float isc2 = 1.f / (float)(m2 * m2);
      int bank;
      if (j1 == 0) bank = j2;            // PSI[(0,j2)]
      else if (j1 == 1) bank = j2 + 2;   // PSI[(1,1)]->4, PSI[(1,2)]->5
      else bank = 6;                     // PSI[(2,1)]
      const int pairIdx = (j1 == 0) ? (j2 - 1) : ((j1 == 1) ? (j2 + 1) : 5);
      const int chb = 33 + 64 * pairIdx;
      const int nchunk = (j1 == 0 && j2 == 1) ? 2 : 1;   // keep buffers <= 64 MiB
      const int nB = 16 / nchunk;
      for (int cc = 0; cc < nchunk; cc++) {
        const int b0 = cc * nB;
        const int nimg = nB * 64;        // (b,l1,l2)
        const float2* u1fsrc = U1F + (long)b0 * 8 * m1 * m1;
        // u2 = |ifft_m2(fold(u1f * psi_(j1,j2-j1)))|
        { RftParams p = rp0(); p.inMode = IN_MULFOLD; p.srcC = u1fsrc; p.filt = PSI + psioff[bank]; p.m1 = m1; p.srcDiv = 8; p.filtMod = 8; p.scale = isc1; p.sign = 1.f; p.outMode = OUT_COMPLEX; p.dstC = BUF1; rft_go(m2, nimg, p, stream); }
        { RftParams p = rp0(); p.inMode = IN_COMPLEX; p.srcC = BUF1; p.sign = 1.f; p.outMode = OUT_ABS; p.dstR = (float*)BUF2; rft_go(m2, nimg, p, stream); }
        // u2f = fft2(u2)
        { RftParams p = rp0(); p.inMode = IN_REAL; p.srcR = (const float*)BUF2; p.sign = -1.f; p.outMode = OUT_COMPLEX; p.dstC = BUF1; rft_go(m2, nimg, p, stream); }
        { RftParams p = rp0(); p.inMode = IN_COMPLEX; p.srcC = BUF1; p.sign = -1.f; p.outMode = OUT_COMPLEX; p.dstC = BUF2; rft_go(m2, nimg, p, stream); }
        // s2 = Re(ifft16(fold(u2f * phi_j2)))
        { RftParams p = rp0(); p.inMode = IN_MULFOLD; p.srcC = BUF2; p.filt = PHI + phioff[j2]; p.m1 = m2; p.srcDiv = 1; p.filtMod = 1; p.scale = isc2; p.sign = 1.f; p.outMode = OUT_COMPLEX; p.dstC = BUF1; rft_go(16, nimg, p, stream); }
        { RftParams p = rp0(); p.inMode = IN_COMPLEX; p.srcC = BUF1; p.sign = 1.f; p.outMode = OUT_REAL_S; p.dstR = S; p.chDiv = 64; p.chBase = chb; p.b0 = b0; rft_go(16, nimg, p, stream); }
      }
    }
  }

  // ---- MLP ----
  hipMemsetAsync(OUT1, 0, 16 * 1024 * 4, stream);
  mlp1_kernel<<<dim3(4, 417), 256, 0, stream>>>(S, w1, OUT1);
  l1post_kernel<<<64, 256, 0, stream>>>(OUT1, b1, bn1g, bn1b, bn1m, bn1v, H1);
  mlp2_kernel<<<2, 256, 0, stream>>>(H1, w2, b2, bn2g, bn2b, bn2m, bn2v, H2);
  mlp3_kernel<<<1, 128, 0, stream>>>(H2, w3, b3, bn3g, bn3b, bn3m, bn3v, H3);
  mlp4_kernel<<<1, 64, 0, stream>>>(H3, w4, b4, (float*)d_out);
}

// Round 2
// 2427.836 us; speedup vs baseline: 9.3081x; 9.3081x over previous
//
#include <hip/hip_runtime.h>
#include <math.h>
#include <string.h>

#define PI_D 3.14159265358979323846264338327950288

// ---------------------------------------------------------------------------
// Scattering2D (J=4, L=8, 256x256, B=16) + MLP, all fp32.
// 2D FFT = row-Stockham-FFT-with-transposed-write applied twice.
// Subsampling is done as spectrum folding fused into pass-1 load.
// ---------------------------------------------------------------------------

enum { IN_COMPLEX = 0, IN_REAL = 1, IN_MULFOLD = 2 };
enum { OUT_COMPLEX = 0, OUT_ABS = 1, OUT_REAL_S = 2 };

struct RftParams {
  const float2* srcC;
  const float*  srcR;
  const float*  filt;
  float2* dstC;
  float*  dstR;
  int m1;        // source resolution for MULFOLD
  int srcDiv;    // source image = img / srcDiv
  int filtMod;   // filter index = img % filtMod
  float scale;   // ifft scale (1/m1^2), applied at load
  float sign;    // -1 forward, +1 inverse
  int chDiv, chBase, b0;   // S-write addressing
  int inMode, outMode;
};

template<int M>
__global__ __launch_bounds__(256) void rft_kernel(RftParams p) {
  constexpr int R = (M >= 64) ? 8 : ((M == 32) ? 16 : 32);   // rows per block
  constexpr int T = (M == 16) ? 4 : ((M == 32) ? 5 : ((M == 64) ? 6 : ((M == 128) ? 7 : 8)));
  __shared__ float2 Abuf[R][M + 1];
  __shared__ float2 Bbuf[R][M + 1];
  __shared__ float2 W[M / 2];
  const int tid = threadIdx.x;
  const long rows0 = (long)blockIdx.x * R;

  // twiddle table: W[q] = exp(sign * 2*pi*i * q / M)
  {
    const float base = p.sign * 6.28318530717958647692f / (float)M;
    for (int i = tid; i < M / 2; i += 256) {
      float sv, cv;
      sincosf(base * (float)i, &sv, &cv);
      W[i] = make_float2(cv, sv);
    }
  }

  // ---- load R rows of length M into Abuf ----
  if (p.inMode == IN_COMPLEX) {
    const float2* s = p.srcC + rows0 * M;
    for (int idx = tid; idx < R * M; idx += 256)
      Abuf[idx / M][idx % M] = s[idx];
  } else if (p.inMode == IN_REAL) {
    const float* s = p.srcR + rows0 * M;
    for (int idx = tid; idx < R * M; idx += 256)
      Abuf[idx / M][idx % M] = make_float2(s[idx], 0.f);
  } else {  // IN_MULFOLD: spectrum * filter, folded from m1^2 down to M^2
    const int m1 = p.m1;
    const int k = m1 / M;
    for (int idx = tid; idx < R * M; idx += 256) {
      const int rl = idx / M, c = idx % M;
      const long g = rows0 + rl;
      const long img = g / M;
      const int r = (int)(g - img * M);
      const float2* sp = p.srcC + (img / p.srcDiv) * (long)m1 * m1;
      const float* fp = p.filt + (long)(img % p.filtMod) * m1 * m1;
      float re = 0.f, im = 0.f;
      for (int qr = 0; qr < k; qr++) {
        const long ro = (long)(r + qr * M) * m1;
        const float2* srow = sp + ro;
        const float*  frow = fp + ro;
        for (int qc = 0; qc < k; qc++) {
          const int cc = c + qc * M;
          const float2 v = srow[cc];
          const float fv = frow[cc];
          re = fmaf(v.x, fv, re);
          im = fmaf(v.y, fv, im);
        }
      }
      Abuf[rl][c] = make_float2(re * p.scale, im * p.scale);
    }
  }
  __syncthreads();

  // ---- Stockham radix-2 DIF (autosort), T stages, ping-pong A<->B ----
  #pragma unroll
  for (int t = 0; t < T; t++) {
    const int s = 1 << t;
    float2 (*Src)[M + 1] = (t & 1) ? Bbuf : Abuf;
    float2 (*Dst)[M + 1] = (t & 1) ? Abuf : Bbuf;
    for (int bf = tid; bf < R * (M / 2); bf += 256) {
      const int row = bf / (M / 2);
      const int j = bf - row * (M / 2);
      const float2 a = Src[row][j];
      const float2 b = Src[row][j + M / 2];
      const float2 w = W[j & ~(s - 1)];
      const float vx = a.x - b.x, vy = a.y - b.y;
      const int dc = (j & (s - 1)) + ((j >> t) << (t + 1));
      Dst[row][dc] = make_float2(a.x + b.x, a.y + b.y);
      Dst[row][dc + s] = make_float2(vx * w.x - vy * w.y, vx * w.y + vy * w.x);
    }
    __syncthreads();
  }
  float2 (*P)[M + 1] = (T & 1) ? Bbuf : Abuf;

  // ---- store transposed: out[img][fo][rpos] = FFT(row rpos)[fo] ----
  if (p.outMode == OUT_COMPLEX) {
    for (int idx = tid; idx < R * M; idx += 256) {
      const int rl = idx & (R - 1);
      const int fo = idx / R;
      const long g = rows0 + rl;
      const long img = g / M;
      const int rpos = (int)(g - img * M);
      p.dstC[img * (long)M * M + (long)fo * M + rpos] = P[rl][fo];
    }
  } else if (p.outMode == OUT_ABS) {
    for (int idx = tid; idx < R * M; idx += 256) {
      const int rl = idx & (R - 1);
      const int fo = idx / R;
      const long g = rows0 + rl;
      const long img = g / M;
      const int rpos = (int)(g - img * M);
      const float2 z = P[rl][fo];
      p.dstR[img * (long)M * M + (long)fo * M + rpos] = sqrtf(z.x * z.x + z.y * z.y);
    }
  } else {  // OUT_REAL_S (M == 16): scatter Re into S[b][ch][16][16]
    for (int idx = tid; idx < R * M; idx += 256) {
      const int rl = idx & (R - 1);
      const int fo = idx / R;
      const long g = rows0 + rl;
      const long img = g / M;
      const int rpos = (int)(g - img * M);
      const int bidx = (int)(img / p.chDiv) + p.b0;
      const int ch = p.chBase + (int)(img % p.chDiv);
      p.dstR[((long)bidx * 417 + ch) * 256 + fo * M + rpos] = P[rl][fo].x;
    }
  }
}

static void rft_go(int M, int nimg, const RftParams& p, hipStream_t st) {
  const int R = (M >= 64) ? 8 : ((M == 32) ? 16 : 32);
  const int blocks = nimg * M / R;
  switch (M) {
    case 256: rft_kernel<256><<<blocks, 256, 0, st>>>(p); break;
    case 128: rft_kernel<128><<<blocks, 256, 0, st>>>(p); break;
    case  64: rft_kernel< 64><<<blocks, 256, 0, st>>>(p); break;
    case  32: rft_kernel< 32><<<blocks, 256, 0, st>>>(p); break;
    case  16: rft_kernel< 16><<<blocks, 256, 0, st>>>(p); break;
  }
}

// ---------------------------------------------------------------------------
// Filter banks (computed on device in f64, mirroring numpy exactly)
// PSI banks: (r,js) = (0,0)(0,1)(0,2)(0,3)(1,1)(1,2)(2,1), 8 orientations each
// ---------------------------------------------------------------------------
__device__ const long PSI_CUM[7] = {524288, 1048576, 1572864, 2097152, 2228224, 2359296, 2392064};
__device__ const int  PSI_MM[7]  = {256, 256, 256, 256, 128, 128, 64};
__device__ const int  PSI_JS[7]  = {0, 1, 2, 3, 1, 2, 1};

__device__ __forceinline__ double dfreq(int i, int m) {
  return (double)((i < (m >> 1)) ? i : i - m) / (double)m;
}

// Grid is exactly 9344*256 = 2392064 threads; every 256-thread block lies
// entirely within one (bank, l) slice (all slice sizes/bases are multiples
// of 256), so one atomicMax per BLOCK suffices (9344 atomics vs 2.39M --
// the per-thread version serialized at ~20 ms, R1 counters: VALUBusy 0.1%).
__global__ __launch_bounds__(256) void build_psi_kernel(float* psi, int* fmax) {
  const long i = (long)blockIdx.x * 256 + threadIdx.x;
  int bank = 0;
  while (i >= PSI_CUM[bank]) bank++;
  const long base = bank ? PSI_CUM[bank - 1] : 0;
  const long rem = i - base;
  const int m = PSI_MM[bank], js = PSI_JS[bank];
  const long mm2 = (long)m * m;
  const int l = (int)(rem / mm2);
  const long pos = rem - (long)l * mm2;
  const int r = (int)(pos / m), c = (int)(pos - (long)r * m);
  const double sigma = 0.8 * (double)(1 << js);
  const double xi = (3.0 * PI_D / 4.0) / (double)(1 << js);
  const double th = (double)l * PI_D / 8.0;
  const double kx = 2.0 * PI_D * dfreq(r, m);
  const double ky = 2.0 * PI_D * dfreq(c, m);
  const double ct = cos(th), st = sin(th);
  const double w1 = kx * ct + ky * st;
  const double w2 = -kx * st + ky * ct;
  const double s2 = sigma * sigma;
  const double aa  = exp(-0.5 * s2 * ((w1 - xi) * (w1 - xi) + 0.25 * w2 * w2));
  const double env = exp(-0.5 * s2 * (w1 * w1 + 0.25 * w2 * w2));
  const double beta = exp(-0.5 * s2 * xi * xi);
  const double f = aa - beta * env;
  psi[i] = (float)f;

  // two-level max reduction: wave shuffle -> LDS -> one atomic per block
  float v = fmaxf((float)f, 0.f);
  #pragma unroll
  for (int off = 32; off > 0; off >>= 1)
    v = fmaxf(v, __shfl_down(v, off, 64));
  __shared__ float wmax[4];
  const int lane = threadIdx.x & 63, wid = threadIdx.x >> 6;
  if (lane == 0) wmax[wid] = v;
  __syncthreads();
  if (threadIdx.x == 0) {
    const float mv = fmaxf(fmaxf(wmax[0], wmax[1]), fmaxf(wmax[2], wmax[3]));
    // max is positive (~0.97); int-compare valid for non-negative floats
    atomicMax(&fmax[bank * 8 + l], __float_as_int(mv));
  }
}

__global__ void norm_psi_kernel(float* psi, const int* fmax) {
  const long i = (long)blockIdx.x * 256 + threadIdx.x;
  if (i >= 2392064L) return;
  int bank = 0;
  while (i >= PSI_CUM[bank]) bank++;
  const long base = bank ? PSI_CUM[bank - 1] : 0;
  const long rem = i - base;
  const int m = PSI_MM[bank];
  const int l = (int)(rem / ((long)m * m));
  const float mx = fmaxf(__int_as_float(fmax[bank * 8 + l]), 1e-12f);
  psi[i] = psi[i] / mx;
}

__global__ void build_phi_kernel(float* phi) {
  const long i = (long)blockIdx.x * 256 + threadIdx.x;
  if (i >= 87040L) return;
  int rr; long base;
  if (i < 65536) { rr = 0; base = 0; }
  else if (i < 81920) { rr = 1; base = 65536; }
  else if (i < 86016) { rr = 2; base = 81920; }
  else { rr = 3; base = 86016; }
  const int m = 256 >> rr;
  const double sigma = 0.8 * (double)(1 << (4 - rr));
  const long pos = i - base;
  const int r = (int)(pos / m), c = (int)(pos % m);
  const double kx = 2.0 * PI_D * dfreq(r, m);
  const double ky = 2.0 * PI_D * dfreq(c, m);
  phi[i] = (float)exp(-0.5 * sigma * sigma * (kx * kx + ky * ky));
}

// ---------------------------------------------------------------------------
// MLP
// ---------------------------------------------------------------------------
__global__ __launch_bounds__(256) void mlp1_kernel(const float* __restrict__ S,
                                                   const float* __restrict__ w1,
                                                   float* __restrict__ out1) {
  __shared__ float hs[16][256];
  const int o = blockIdx.x * 256 + threadIdx.x;   // 1024 outputs over 4 blocks
  const int ch = blockIdx.y;                      // 417 k-chunks of 256
  for (int idx = threadIdx.x; idx < 16 * 256; idx += 256) {
    const int b = idx >> 8, kk = idx & 255;
    hs[b][kk] = S[((long)b * 417 + ch) * 256 + kk];
  }
  __syncthreads();
  float acc[16];
  #pragma unroll
  for (int b = 0; b < 16; b++) acc[b] = 0.f;
  const float* wp = w1 + (long)ch * 256 * 1024 + o;
  for (int kk = 0; kk < 256; kk++) {
    const float w = wp[(long)kk * 1024];
    #pragma unroll
    for (int b = 0; b < 16; b++) acc[b] = fmaf(hs[b][kk], w, acc[b]);
  }
  #pragma unroll
  for (int b = 0; b < 16; b++) atomicAdd(&out1[b * 1024 + o], acc[b]);
}

__global__ void l1post_kernel(const float* out1, const float* b1, const float* g,
                              const float* bb, const float* mm, const float* vv, float* h1) {
  const int i = blockIdx.x * 256 + threadIdx.x;
  if (i < 16384) {
    const int o = i & 1023;
    const float xv = fmaxf(out1[i] + b1[o], 0.f);
    const float rs = (float)(1.0 / sqrt((double)vv[o] + 1e-5));
    h1[i] = (xv - mm[o]) * rs * g[o] + bb[o];
  }
}

__global__ __launch_bounds__(256) void mlp2_kernel(const float* h1, const float* w2, const float* b2,
                                                   const float* g, const float* bb, const float* mm,
                                                   const float* vv, float* h2) {
  __shared__ float hs[16][256];
  const int o = blockIdx.x * 256 + threadIdx.x;   // 512 outputs over 2 blocks
  float acc[16];
  #pragma unroll
  for (int b = 0; b < 16; b++) acc[b] = 0.f;
  for (int kc = 0; kc < 4; kc++) {
    __syncthreads();
    for (int idx = threadIdx.x; idx < 16 * 256; idx += 256) {
      const int b = idx >> 8, kk = idx & 255;
      hs[b][kk] = h1[b * 1024 + kc * 256 + kk];
    }
    __syncthreads();
    for (int kk = 0; kk < 256; kk++) {
      const float w = w2[(long)(kc * 256 + kk) * 512 + o];
      #pragma unroll
      for (int b = 0; b < 16; b++) acc[b] = fmaf(hs[b][kk], w, acc[b]);
    }
  }
  const float bias = b2[o], gg = g[o], bbv = bb[o], mv = mm[o];
  const float rs = (float)(1.0 / sqrt((double)vv[o] + 1e-5));
  for (int b = 0; b < 16; b++) {
    const float xv = fmaxf(acc[b] + bias, 0.f);
    h2[b * 512 + o] = (xv - mv) * rs * gg + bbv;
  }
}

__global__ __launch_bounds__(128) void mlp3_kernel(const float* h2, const float* w3, const float* b3,
                                                   const float* g, const float* bb, const float* mm,
                                                   const float* vv, float* h3) {
  __shared__ float hs[16][256];
  const int o = threadIdx.x;   // 128 outputs
  float acc[16];
  #pragma unroll
  for (int b = 0; b < 16; b++) acc[b] = 0.f;
  for (int kc = 0; kc < 2; kc++) {
    __syncthreads();
    for (int idx = threadIdx.x; idx < 16 * 256; idx += 128) {
      const int b = idx >> 8, kk = idx & 255;
      hs[b][kk] = h2[b * 512 + kc * 256 + kk];
    }
    __syncthreads();
    for (int kk = 0; kk < 256; kk++) {
      const float w = w3[(kc * 256 + kk) * 128 + o];
      #pragma unroll
      for (int b = 0; b < 16; b++) acc[b] = fmaf(hs[b][kk], w, acc[b]);
    }
  }
  const float bias = b3[o], gg = g[o], bbv = bb[o], mv = mm[o];
  const float rs = (float)(1.0 / sqrt((double)vv[o] + 1e-5));
  for (int b = 0; b < 16; b++) {
    const float xv = fmaxf(acc[b] + bias, 0.f);
    h3[b * 128 + o] = (xv - mv) * rs * gg + bbv;
  }
}

__global__ void mlp4_kernel(const float* h3, const float* w4, const float* b4, float* out) {
  const int b = threadIdx.x;
  if (b < 16) {
    double a = 0.0;
    for (int k = 0; k < 128; k++) a += (double)h3[b * 128 + k] * (double)w4[k];
    out[b] = (float)(a + (double)b4[0]);
  }
}

// ---------------------------------------------------------------------------
// Orchestration
// ---------------------------------------------------------------------------
static RftParams rp0() {
  RftParams p;
  memset(&p, 0, sizeof(p));
  p.srcDiv = 1; p.filtMod = 1; p.chDiv = 1;
  p.scale = 1.f; p.sign = -1.f; p.m1 = 0;
  return p;
}

extern "C" void kernel_launch(void* const* d_in, const int* in_sizes, int n_in,
                              void* d_out, int out_size, void* d_ws, size_t ws_size,
                              hipStream_t stream) {
  (void)in_sizes; (void)n_in; (void)out_size; (void)ws_size;
  const float* x    = (const float*)d_in[0];
  const float* w1   = (const float*)d_in[1];
  const float* b1   = (const float*)d_in[2];
  const float* bn1g = (const float*)d_in[3];
  const float* bn1b = (const float*)d_in[4];
  const float* bn1m = (const float*)d_in[5];
  const float* bn1v = (const float*)d_in[6];
  const float* w2   = (const float*)d_in[7];
  const float* b2   = (const float*)d_in[8];
  const float* bn2g = (const float*)d_in[9];
  const float* bn2b = (const float*)d_in[10];
  const float* bn2m = (const float*)d_in[11];
  const float* bn2v = (const float*)d_in[12];
  const float* w3   = (const float*)d_in[13];
  const float* b3   = (const float*)d_in[14];
  const float* bn3g = (const float*)d_in[15];
  const float* bn3b = (const float*)d_in[16];
  const float* bn3m = (const float*)d_in[17];
  const float* bn3v = (const float*)d_in[18];
  const float* w4   = (const float*)d_in[19];
  const float* b4   = (const float*)d_in[20];

  char* ws = (char*)d_ws;
  float2* XF   = (float2*)(ws + 0);            //  8 MiB: fft2(x), 16 x 256^2
  float2* U1F  = (float2*)(ws + 8388608);      // 64 MiB: fft2(u1), up to 128 x 256^2
  float2* BUF1 = (float2*)(ws + 75497472);     // 64 MiB ping
  float2* BUF2 = (float2*)(ws + 142606336);    // 64 MiB pong (u1/u2 real alias here)
  float*  S    = (float*)(ws + 209715200);     // 16 x 417 x 256 scattering output
  float*  PSI  = (float*)(ws + 216547328);     // 2392064 floats
  float*  PHI  = (float*)(ws + 226115584);     // 87040 floats
  int*    FMAX = (int*)(ws + 226463744);       // 56 slots
  float*  OUT1 = (float*)(ws + 226464000);     // 16 x 1024
  float*  H1   = (float*)(ws + 226529536);
  float*  H2   = (float*)(ws + 226595072);
  float*  H3   = (float*)(ws + 226627840);

  static const int psioff[7] = {0, 524288, 1048576, 1572864, 2097152, 2228224, 2359296};
  static const int phioff[4] = {0, 65536, 81920, 86016};

  // ---- filters (deterministic, rebuilt every call) ----
  hipMemsetAsync(FMAX, 0, 256, stream);
  build_psi_kernel<<<9344, 256, 0, stream>>>(PSI, FMAX);
  norm_psi_kernel<<<9344, 256, 0, stream>>>(PSI, FMAX);
  build_phi_kernel<<<340, 256, 0, stream>>>(PHI);

  // ---- Xf = fft2(x) ----
  { RftParams p = rp0(); p.inMode = IN_REAL; p.srcR = x; p.outMode = OUT_COMPLEX; p.dstC = BUF1; p.sign = -1.f; rft_go(256, 16, p, stream); }
  { RftParams p = rp0(); p.inMode = IN_COMPLEX; p.srcC = BUF1; p.outMode = OUT_COMPLEX; p.dstC = XF; p.sign = -1.f; rft_go(256, 16, p, stream); }

  // ---- s0 = Re(ifft16(fold(Xf*phi0))) ----
  { RftParams p = rp0(); p.inMode = IN_MULFOLD; p.srcC = XF; p.filt = PHI + phioff[0]; p.m1 = 256; p.srcDiv = 1; p.filtMod = 1; p.scale = 1.f / 65536.f; p.sign = 1.f; p.outMode = OUT_COMPLEX; p.dstC = BUF1; rft_go(16, 16, p, stream); }
  { RftParams p = rp0(); p.inMode = IN_COMPLEX; p.srcC = BUF1; p.sign = 1.f; p.outMode = OUT_REAL_S; p.dstR = S; p.chDiv = 1; p.chBase = 0; p.b0 = 0; rft_go(16, 16, p, stream); }

  for (int j1 = 0; j1 < 4; j1++) {
    const int m1 = 256 >> j1;
    const float isc1 = 1.f / (float)(m1 * m1);
    // u1 = |ifft_m1(fold(Xf * psi_(0,j1)))|   (128 images: (b,l1))
    { RftParams p = rp0(); p.inMode = IN_MULFOLD; p.srcC = XF; p.filt = PSI + psioff[j1]; p.m1 = 256; p.srcDiv = 8; p.filtMod = 8; p.scale = 1.f / 65536.f; p.sign = 1.f; p.outMode = OUT_COMPLEX; p.dstC = BUF1; rft_go(m1, 128, p, stream); }
    { RftParams p = rp0(); p.inMode = IN_COMPLEX; p.srcC = BUF1; p.sign = 1.f; p.outMode = OUT_ABS; p.dstR = (float*)BUF2; rft_go(m1, 128, p, stream); }
    // u1f = fft2(u1)
    { RftParams p = rp0(); p.inMode = IN_REAL; p.srcR = (const float*)BUF2; p.sign = -1.f; p.outMode = OUT_COMPLEX; p.dstC = BUF1; rft_go(m1, 128, p, stream); }
    { RftParams p = rp0(); p.inMode = IN_COMPLEX; p.srcC = BUF1; p.sign = -1.f; p.outMode = OUT_COMPLEX; p.dstC = U1F; rft_go(m1, 128, p, stream); }
    // s1 = Re(ifft16(fold(u1f * phi_j1)))
    { RftParams p = rp0(); p.inMode = IN_MULFOLD; p.srcC = U1F; p.filt = PHI + phioff[j1]; p.m1 = m1; p.srcDiv = 1; p.filtMod = 1; p.scale = isc1; p.sign = 1.f; p.outMode = OUT_COMPLEX; p.dstC = BUF1; rft_go(16, 128, p, stream); }
    { RftParams p = rp0(); p.inMode = IN_COMPLEX; p.srcC = BUF1; p.sign = 1.f; p.outMode = OUT_REAL_S; p.dstR = S; p.chDiv = 8; p.chBase = 1 + 8 * j1; p.b0 = 0; rft_go(16, 128, p, stream); }

    for (int j2 = j1 + 1; j2 < 4; j2++) {
      const int m2 = 256 >> j2;
      const float isc2 = 1.f / (float)(m2 * m2);
      int bank;
      if (j1 == 0) bank = j2;            // PSI[(0,j2)]
      else if (j1 == 1) bank = j2 + 2;   // PSI[(1,1)]->4, PSI[(1,2)]->5
      else bank = 6;                     // PSI[(2,1)]
      const int pairIdx = (j1 == 0) ? (j2 - 1) : ((j1 == 1) ? (j2 + 1) : 5);
      const int chb = 33 + 64 * pairIdx;
      const int nchunk = (j1 == 0 && j2 == 1) ? 2 : 1;   // keep buffers <= 64 MiB
      const int nB = 16 / nchunk;
      for (int cc = 0; cc < nchunk; cc++) {
        const int b0 = cc * nB;
        const int nimg = nB * 64;        // (b,l1,l2)
        const float2* u1fsrc = U1F + (long)b0 * 8 * m1 * m1;
        // u2 = |ifft_m2(fold(u1f * psi_(j1,j2-j1)))|
        { RftParams p = rp0(); p.inMode = IN_MULFOLD; p.srcC = u1fsrc; p.filt = PSI + psioff[bank]; p.m1 = m1; p.srcDiv = 8; p.filtMod = 8; p.scale = isc1; p.sign = 1.f; p.outMode = OUT_COMPLEX; p.dstC = BUF1; rft_go(m2, nimg, p, stream); }
        { RftParams p = rp0(); p.inMode = IN_COMPLEX; p.srcC = BUF1; p.sign = 1.f; p.outMode = OUT_ABS; p.dstR = (float*)BUF2; rft_go(m2, nimg, p, stream); }
        // u2f = fft2(u2)
        { RftParams p = rp0(); p.inMode = IN_REAL; p.srcR = (const float*)BUF2; p.sign = -1.f; p.outMode = OUT_COMPLEX; p.dstC = BUF1; rft_go(m2, nimg, p, stream); }
        { RftParams p = rp0(); p.inMode = IN_COMPLEX; p.srcC = BUF1; p.sign = -1.f; p.outMode = OUT_COMPLEX; p.dstC = BUF2; rft_go(m2, nimg, p, stream); }
        // s2 = Re(ifft16(fold(u2f * phi_j2)))
        { RftParams p = rp0(); p.inMode = IN_MULFOLD; p.srcC = BUF2; p.filt = PHI + phioff[j2]; p.m1 = m2; p.srcDiv = 1; p.filtMod = 1; p.scale = isc2; p.sign = 1.f; p.outMode = OUT_COMPLEX; p.dstC = BUF1; rft_go(16, nimg, p, stream); }
        { RftParams p = rp0(); p.inMode = IN_COMPLEX; p.srcC = BUF1; p.sign = 1.f; p.outMode = OUT_REAL_S; p.dstR = S; p.chDiv = 64; p.chBase = chb; p.b0 = b0; rft_go(16, nimg, p, stream); }
      }
    }
  }

  // ---- MLP ----
  hipMemsetAsync(OUT1, 0, 16 * 1024 * 4, stream);
  mlp1_kernel<<<dim3(4, 417), 256, 0, stream>>>(S, w1, OUT1);
  l1post_kernel<<<64, 256, 0, stream>>>(OUT1, b1, bn1g, bn1b, bn1m, bn1v, H1);
  mlp2_kernel<<<2, 256, 0, stream>>>(H1, w2, b2, bn2g, bn2b, bn2m, bn2v, H2);
  mlp3_kernel<<<1, 128, 0, stream>>>(H2, w3, b3, bn3g, bn3b, bn3m, bn3v, H3);
  mlp4_kernel<<<1, 64, 0, stream>>>(H3, w4, b4, (float*)d_out);
}